// Round 4
// baseline (123.988 us; speedup 1.0000x reference)
//
#include <hip/hip_runtime.h>
#include <stdint.h>

// Problem constants (fixed by the reference)
#define NB    32768   // batch
#define NS    16      // states per element
#define SS    32      // state size (K of stage 1)
#define ENCD  64      // encoder width
#define HIDD  128     // hidden width
#define OUTD  8       // output logits
#define BT    16      // batch elements per block
#define THREADS 256   // 4 waves

// Pre-split weight fragment regions in d_ws (units: half8 = 16 B per lane-entry).
// Each fragment = 64 lanes x half8, stored in lane order -> one dwordx4 per lane.
#define WE_FRAGS 8            // W_enc : nt(4) x part(2)
#define WF_FRAGS 64           // W_f   : nt(8) x ks(4) x part(2)
#define WD_FRAGS 8            // W_dec : ks(4) x part(2)
#define WE_OFF 0
#define WF_OFF (WE_FRAGS)
#define WD_OFF (WE_FRAGS + WF_FRAGS)
// total 80 frags * 64 lanes * 16 B = 80 KiB of d_ws (ws is 256 MB per fill counters)

typedef _Float16 half8  __attribute__((ext_vector_type(8)));  // 8 f16 = 4 VGPRs
typedef __fp16   fp16x2 __attribute__((ext_vector_type(2)));  // cvt_pkrtz result type
typedef float    f32x4  __attribute__((ext_vector_type(4)));

#define MFMA(a, b, c) __builtin_amdgcn_mfma_f32_16x16x32_f16((a), (b), (c), 0, 0, 0)

// Split 8 floats into fp16 hi + lo: f = hi + lo + O(2^-20 |f|).
__device__ __forceinline__ void split8(const float* f, half8& hi, half8& lo) {
#pragma unroll
  for (int j = 0; j < 8; j += 2) {
    fp16x2 h  = __builtin_amdgcn_cvt_pkrtz(f[j], f[j + 1]);
    float  r0 = f[j]     - (float)h[0];
    float  r1 = f[j + 1] - (float)h[1];
    fp16x2 l2 = __builtin_amdgcn_cvt_pkrtz(r0, r1);
    hi[j] = (_Float16)(float)h[0];  hi[j + 1] = (_Float16)(float)h[1];
    lo[j] = (_Float16)(float)l2[0]; lo[j + 1] = (_Float16)(float)l2[1];
  }
}

// ---- prep kernel: split weights into MFMA B-fragment lane order, once per launch
// B-frag layout for 16x16x32: lane (quad=l>>4, m15=l&15) holds B[k=quad*8+j][n=m15]
// grid = 10 blocks x 256: entries 0..255 W_enc, 256..2303 W_f, 2304..2559 W_dec
__global__ void prep_weights(const float* __restrict__ We,
                             const float* __restrict__ Wf,
                             const float* __restrict__ Wd,
                             _Float16* __restrict__ ws) {
  const int g = blockIdx.x * 256 + threadIdx.x;
  half8* frag = (half8*)ws;
  float f[8];
  half8 hi, lo;
  if (g < 256) {                                  // W_enc: nt(4) x lanes(64)
    const int nt = g >> 6, l = g & 63, quad = l >> 4, m15 = l & 15;
#pragma unroll
    for (int j = 0; j < 8; ++j)
      f[j] = We[(size_t)(quad * 8 + j) * ENCD + nt * 16 + m15];
    split8(f, hi, lo);
    frag[(WE_OFF + nt * 2 + 0) * 64 + l] = hi;
    frag[(WE_OFF + nt * 2 + 1) * 64 + l] = lo;
  } else if (g < 256 + 2048) {                    // W_f: nt(8) x ks(4) x lanes(64)
    const int e = g - 256;
    const int nt = e >> 8, ks = (e >> 6) & 3, l = e & 63, quad = l >> 4, m15 = l & 15;
#pragma unroll
    for (int j = 0; j < 8; ++j)
      f[j] = Wf[(size_t)(ks * 32 + quad * 8 + j) * HIDD + nt * 16 + m15];
    split8(f, hi, lo);
    frag[(WF_OFF + (nt * 4 + ks) * 2 + 0) * 64 + l] = hi;
    frag[(WF_OFF + (nt * 4 + ks) * 2 + 1) * 64 + l] = lo;
  } else {                                        // W_dec: ks(4) x lanes(64), N padded 8->16
    const int e = g - 2304;
    const int ks = e >> 6, l = e & 63, quad = l >> 4, m15 = l & 15;
#pragma unroll
    for (int j = 0; j < 8; ++j)
      f[j] = (m15 < OUTD) ? Wd[(size_t)(ks * 32 + quad * 8 + j) * OUTD + m15] : 0.f;
    split8(f, hi, lo);
    frag[(WD_OFF + ks * 2 + 0) * 64 + l] = hi;
    frag[(WD_OFF + ks * 2 + 1) * 64 + l] = lo;
  }
}

__global__ __launch_bounds__(THREADS, 6)
void gnn_fused(const float* __restrict__ obs,
               const float* __restrict__ b_enc,
               const float* __restrict__ b_f,
               const float* __restrict__ b_dec,
               const _Float16* __restrict__ wsf,
               float* __restrict__ out)
{
  // stride 132 floats: rows 528 B (16B-aligned), row-to-row bank shift of 4
  __shared__ __align__(16) float f_in[BT][132];   // stage-2 output [batch][128]
  __shared__ __align__(16) float hidn[BT][132];   // stage-3 output [batch][128]

  const half8* frag = (const half8*)wsf;
  const int tid  = threadIdx.x;
  const int w    = tid >> 6;     // wave 0..3
  const int l    = tid & 63;     // lane
  const int m15  = l & 15;
  const int quad = l >> 4;
  const int b0   = blockIdx.x * BT;

  // ---- stage-1 B-fragments: one dwordx4 per fragment (L2-broadcast)
  half8 we_hi[4], we_lo[4];
  float benc[4];
#pragma unroll
  for (int nt = 0; nt < 4; ++nt) {
    we_hi[nt] = frag[(WE_OFF + nt * 2 + 0) * 64 + l];
    we_lo[nt] = frag[(WE_OFF + nt * 2 + 1) * 64 + l];
    benc[nt]  = b_enc[nt * 16 + m15];
  }

  // ================= stage 1 (enc MFMA) + stage 2 (masked mean-pool) =========
  // wave handles batches [b0 + w*4, b0 + w*4 + 4)
  // lane's A-fragment = states[b][m15][quad*8 .. +8) : 32 contiguous bytes in HBM
  const float* bp = obs + (size_t)(b0 + w * 4) * (NS * SS) + m15 * SS + quad * 8;
  float4 cc0[4], cc1[4];
#pragma unroll
  for (int i = 0; i < 2; ++i) {                   // 2-deep preload
    const float* p = bp + (size_t)i * (NS * SS);
    cc0[i] = ((const float4*)p)[0];
    cc1[i] = ((const float4*)p)[1];
  }
#pragma unroll
  for (int i = 0; i < 4; ++i) {
    if (i < 2) {                                  // keep 2 loads in flight
      const float* p = bp + (size_t)(i + 2) * (NS * SS);
      cc0[i + 2] = ((const float4*)p)[0];
      cc1[i + 2] = ((const float4*)p)[1];
    }
    float f[8] = {cc0[i].x, cc0[i].y, cc0[i].z, cc0[i].w,
                  cc1[i].x, cc1[i].y, cc1[i].z, cc1[i].w};

    // flags: lanes 0..15 hold states[b][n][0]; cumprod run length via ballot+ctz
    unsigned long long bal = __ballot((l < 16) && (f[0] == 1.0f));
    int run = __builtin_ctzll(~(bal >> 1));       // consecutive valid neighbors, 0..15
    float inv = 1.0f / fmaxf((float)run, 1.0f);

    half8 ahi, alo;
    split8(f, ahi, alo);

    const int bi = w * 4 + i;  // local batch row
#pragma unroll
    for (int nt = 0; nt < 4; ++nt) {
      f32x4 acc = {0.f, 0.f, 0.f, 0.f};
      acc = MFMA(ahi, we_hi[nt], acc);
      acc = MFMA(alo, we_hi[nt], acc);
      acc = MFMA(ahi, we_lo[nt], acc);
      // D layout: lane holds enc[n = quad*4 + r][e = nt*16 + m15]
      float s = 0.f, e0 = 0.f;
#pragma unroll
      for (int r = 0; r < 4; ++r) {
        int n = quad * 4 + r;
        float v = fmaxf(acc[r] + benc[nt], 0.f);
        if (n == 0) e0 = v;                       // agent row
        if (n >= 1 && n <= run) s += v;           // valid neighbor
      }
      s += __shfl_xor(s, 16, 64);                 // reduce across quads
      s += __shfl_xor(s, 32, 64);
      if (quad == 0) {
        f_in[bi][nt * 16 + m15]      = e0;        // agent_enc
        f_in[bi][64 + nt * 16 + m15] = s * inv;   // agg
      }
    }
  }
  __syncthreads();

  // ================= stage 3: hidden = relu(f_in @ W_f + b_f) ================
  // single 16-row M-tile; wave w covers N-tiles 2w, 2w+1
  {
    half8 fa_hi[4], fa_lo[4];
#pragma unroll
    for (int ks = 0; ks < 4; ++ks) {
      const float4* p = (const float4*)&f_in[m15][ks * 32 + quad * 8];
      float4 a = p[0], b = p[1];
      float f[8] = {a.x, a.y, a.z, a.w, b.x, b.y, b.z, b.w};
      split8(f, fa_hi[ks], fa_lo[ks]);
    }

#pragma unroll
    for (int tt = 0; tt < 2; ++tt) {
      const int ntile = w * 2 + tt;
      const int h0 = ntile * 16 + m15;            // output column
      f32x4 acc = {0.f, 0.f, 0.f, 0.f};
#pragma unroll
      for (int ks = 0; ks < 4; ++ks) {
        half8 bhi = frag[(WF_OFF + (ntile * 4 + ks) * 2 + 0) * 64 + l];
        half8 blo = frag[(WF_OFF + (ntile * 4 + ks) * 2 + 1) * 64 + l];
        acc = MFMA(fa_hi[ks], bhi, acc);
        acc = MFMA(fa_lo[ks], bhi, acc);
        acc = MFMA(fa_hi[ks], blo, acc);
      }
      const float bfv = b_f[h0];
#pragma unroll
      for (int r = 0; r < 4; ++r)                 // D: row = batch, col = h0
        hidn[quad * 4 + r][h0] = fmaxf(acc[r] + bfv, 0.f);
    }
  }
  __syncthreads();

  // ================= stage 4: logits = hidden @ W_dec + b_dec ================
  if (w == 0) {                                   // one 16-row M-tile
    half8 ga_hi[4], ga_lo[4];
#pragma unroll
    for (int ks = 0; ks < 4; ++ks) {
      const float4* p = (const float4*)&hidn[m15][ks * 32 + quad * 8];
      float4 a = p[0], b = p[1];
      float f[8] = {a.x, a.y, a.z, a.w, b.x, b.y, b.z, b.w};
      split8(f, ga_hi[ks], ga_lo[ks]);
    }
    f32x4 acc = {0.f, 0.f, 0.f, 0.f};
#pragma unroll
    for (int ks = 0; ks < 4; ++ks) {
      half8 bhi = frag[(WD_OFF + ks * 2 + 0) * 64 + l];
      half8 blo = frag[(WD_OFF + ks * 2 + 1) * 64 + l];
      acc = MFMA(ga_hi[ks], bhi, acc);
      acc = MFMA(ga_lo[ks], bhi, acc);
      acc = MFMA(ga_hi[ks], blo, acc);
    }
    if (m15 < OUTD) {
      const float bd = b_dec[m15];
#pragma unroll
      for (int r = 0; r < 4; ++r) {
        const int m = quad * 4 + r;
        out[(size_t)(b0 + m) * OUTD + m15] = acc[r] + bd;
      }
    }
  }
}

extern "C" void kernel_launch(void* const* d_in, const int* in_sizes, int n_in,
                              void* d_out, int out_size, void* d_ws, size_t ws_size,
                              hipStream_t stream) {
  (void)in_sizes; (void)n_in; (void)ws_size; (void)out_size;
  const float* obs   = (const float*)d_in[0];
  const float* W_enc = (const float*)d_in[1];
  const float* b_enc = (const float*)d_in[2];
  const float* W_f   = (const float*)d_in[3];
  const float* b_f   = (const float*)d_in[4];
  const float* W_dec = (const float*)d_in[5];
  const float* b_dec = (const float*)d_in[6];
  float* out = (float*)d_out;
  _Float16* wsf = (_Float16*)d_ws;                // 80 KiB used

  prep_weights<<<dim3(10), dim3(256), 0, stream>>>(W_enc, W_f, W_dec, wsf);
  gnn_fused<<<dim3(NB / BT), dim3(THREADS), 0, stream>>>(
      obs, b_enc, b_f, b_dec, (const _Float16*)wsf, out);
}

// Round 5
// 114.108 us; speedup vs baseline: 1.0866x; 1.0866x over previous
//
#include <hip/hip_runtime.h>
#include <stdint.h>

// Problem constants (fixed by the reference)
#define NB    32768   // batch
#define NS    16      // states per element
#define SS    32      // state size (K of stage 1)
#define ENCD  64      // encoder width
#define HIDD  128     // hidden width
#define OUTD  8       // output logits
#define BT    16      // batch elements per block
#define THREADS 256   // 4 waves

typedef _Float16 half8 __attribute__((ext_vector_type(8)));  // 8 f16 = 4 VGPRs
typedef float    f32x4 __attribute__((ext_vector_type(4)));

#define MFMA(a, b, c) __builtin_amdgcn_mfma_f32_16x16x32_f16((a), (b), (c), 0, 0, 0)

// 8 floats -> 8 fp16 (RNE via scalar casts; compiler emits v_cvt_f16_f32 + pack)
__device__ __forceinline__ half8 pack8(const float* f) {
  half8 h;
#pragma unroll
  for (int j = 0; j < 8; ++j) h[j] = (_Float16)f[j];
  return h;
}

// Error budget note: single-fp16 inputs w/ fp32 MFMA accumulation. R1 (bf16
// 3-term) and R3 (fp16 3-term) gave IDENTICAL absmax 2^-11 -> floor is not
// split precision. Added quant error here ~5e-4 worst-case, threshold 4.24e-3.
__global__ __launch_bounds__(THREADS, 6)
void gnn_fused(const float* __restrict__ obs,
               const float* __restrict__ W_enc,
               const float* __restrict__ b_enc,
               const float* __restrict__ W_f,
               const float* __restrict__ b_f,
               const float* __restrict__ W_dec,
               const float* __restrict__ b_dec,
               float* __restrict__ out)
{
  // fp16 LDS, row stride 136 halfs = 272 B (16B-aligned rows, odd*4 bank skew)
  __shared__ __align__(16) _Float16 f_in[BT][136];  // stage-2 output [batch][128]
  __shared__ __align__(16) _Float16 hidn[BT][136];  // stage-3 output [batch][128]

  const int tid  = threadIdx.x;
  const int w    = tid >> 6;     // wave 0..3
  const int l    = tid & 63;     // lane
  const int m15  = l & 15;
  const int quad = l >> 4;
  const int b0   = blockIdx.x * BT;

  // ---- stage-1 B-fragments: W_enc[k][e], fp16 single-term, in regs (16 VGPRs)
  half8 we[4];
  float benc[4];
#pragma unroll
  for (int nt = 0; nt < 4; ++nt) {
    float f[8];
#pragma unroll
    for (int j = 0; j < 8; ++j)
      f[j] = W_enc[(size_t)(quad * 8 + j) * ENCD + nt * 16 + m15];
    we[nt]   = pack8(f);
    benc[nt] = b_enc[nt * 16 + m15];
  }

  // ================= stage 1 (enc MFMA) + stage 2 (masked mean-pool) =========
  // wave handles batches [b0 + w*4, b0 + w*4 + 4)
  // lane's A-fragment = states[b][m15][quad*8 .. +8) : 32 contiguous bytes
  const float* bp = obs + (size_t)(b0 + w * 4) * (NS * SS) + m15 * SS + quad * 8;
  float4 c0[4], c1[4];
#pragma unroll
  for (int i = 0; i < 4; ++i) {                 // all 4 elements in flight
    const float* p = bp + (size_t)i * (NS * SS);
    c0[i] = ((const float4*)p)[0];
    c1[i] = ((const float4*)p)[1];
  }
#pragma unroll
  for (int i = 0; i < 4; ++i) {
    float f[8] = {c0[i].x, c0[i].y, c0[i].z, c0[i].w,
                  c1[i].x, c1[i].y, c1[i].z, c1[i].w};

    // flags: lanes 0..15 hold states[b][n][0]; cumprod run length via ballot+ctz
    unsigned long long bal = __ballot((l < 16) && (f[0] == 1.0f));
    int run = __builtin_ctzll(~(bal >> 1));     // consecutive valid neighbors 0..15
    float inv = 1.0f / fmaxf((float)run, 1.0f);

    half8 a = pack8(f);

    const int bi = w * 4 + i;  // local batch row
#pragma unroll
    for (int nt = 0; nt < 4; ++nt) {
      f32x4 acc = {0.f, 0.f, 0.f, 0.f};
      acc = MFMA(a, we[nt], acc);
      // D layout: lane holds enc[n = quad*4 + r][e = nt*16 + m15]
      float s = 0.f, e0 = 0.f;
#pragma unroll
      for (int r = 0; r < 4; ++r) {
        int n = quad * 4 + r;
        float v = fmaxf(acc[r] + benc[nt], 0.f);
        if (n == 0) e0 = v;                     // agent row
        if (n >= 1 && n <= run) s += v;         // valid neighbor
      }
      s += __shfl_xor(s, 16, 64);               // reduce across quads
      s += __shfl_xor(s, 32, 64);
      if (quad == 0) {
        f_in[bi][nt * 16 + m15]      = (_Float16)e0;        // agent_enc
        f_in[bi][64 + nt * 16 + m15] = (_Float16)(s * inv); // agg
      }
    }
  }
  __syncthreads();

  // ================= stage 3: hidden = relu(f_in @ W_f + b_f) ================
  // single 16-row M-tile; wave w covers N-tiles 2w, 2w+1
  {
    half8 fa[4];
#pragma unroll
    for (int ks = 0; ks < 4; ++ks)              // A-frag: one 16B LDS read, no cvt
      fa[ks] = *(const half8*)&f_in[m15][ks * 32 + quad * 8];

#pragma unroll
    for (int tt = 0; tt < 2; ++tt) {
      const int h0 = (w * 2 + tt) * 16 + m15;   // output column
      f32x4 acc = {0.f, 0.f, 0.f, 0.f};
#pragma unroll
      for (int ks = 0; ks < 4; ++ks) {
        float f[8];
#pragma unroll
        for (int j = 0; j < 8; ++j)             // W_f column chunk (L1/L2 hot)
          f[j] = W_f[(size_t)(ks * 32 + quad * 8 + j) * HIDD + h0];
        acc = MFMA(fa[ks], pack8(f), acc);
      }
      const float bfv = b_f[h0];
#pragma unroll
      for (int r = 0; r < 4; ++r)               // D: row = batch, col = h0
        hidn[quad * 4 + r][h0] = (_Float16)fmaxf(acc[r] + bfv, 0.f);
    }
  }
  __syncthreads();

  // ================= stage 4: logits = hidden @ W_dec + b_dec ================
  if (w == 0) {                                 // one 16-row M-tile
    half8 ga[4];
#pragma unroll
    for (int ks = 0; ks < 4; ++ks)
      ga[ks] = *(const half8*)&hidn[m15][ks * 32 + quad * 8];
    f32x4 acc = {0.f, 0.f, 0.f, 0.f};
#pragma unroll
    for (int ks = 0; ks < 4; ++ks) {
      float f[8];
#pragma unroll
      for (int j = 0; j < 8; ++j) {
        int k = ks * 32 + quad * 8 + j;
        f[j] = (m15 < OUTD) ? W_dec[(size_t)k * OUTD + m15] : 0.f;  // pad N 8->16
      }
      acc = MFMA(ga[ks], pack8(f), acc);
    }
    if (m15 < OUTD) {
      const float bd = b_dec[m15];
#pragma unroll
      for (int r = 0; r < 4; ++r) {
        const int m = quad * 4 + r;
        out[(size_t)(b0 + m) * OUTD + m15] = acc[r] + bd;
      }
    }
  }
}

extern "C" void kernel_launch(void* const* d_in, const int* in_sizes, int n_in,
                              void* d_out, int out_size, void* d_ws, size_t ws_size,
                              hipStream_t stream) {
  (void)in_sizes; (void)n_in; (void)d_ws; (void)ws_size; (void)out_size;
  const float* obs   = (const float*)d_in[0];
  const float* W_enc = (const float*)d_in[1];
  const float* b_enc = (const float*)d_in[2];
  const float* W_f   = (const float*)d_in[3];
  const float* b_f   = (const float*)d_in[4];
  const float* W_dec = (const float*)d_in[5];
  const float* b_dec = (const float*)d_in[6];
  float* out = (float*)d_out;

  // single kernel; deliberately does NOT touch d_ws (avoids serializing behind
  // the harness's 256 MB ws-poison fill — R4 lesson)
  gnn_fused<<<dim3(NB / BT), dim3(THREADS), 0, stream>>>(
      obs, W_enc, b_enc, W_f, b_f, W_dec, b_dec, out);
}